// Round 8
// baseline (26.949 us; speedup 1.0000x reference)
//
#include <hip/hip_runtime.h>
#include <math.h>

#define NF 64
#define NC 16
#define LEN 2048
#define BATCH 256
#define BETA 2.5f
#define KAPPA 10.0f
#define EPSN 1e-12f
#define LOG2E 1.4426950408889634f

#define TPB 512
#define NQ (TPB / NF)        // 8 waves per block
#define CHUNK (LEN / NQ)     // 256 t's per thread

typedef float v2f __attribute__((ext_vector_type(2)));

__device__ __forceinline__ float clip01(float v) { return fminf(fmaxf(v, 0.0f), 1.0f); }

__device__ __forceinline__ float fexp2(float x) {
#if __has_builtin(__builtin_amdgcn_exp2f)
    return __builtin_amdgcn_exp2f(x);
#else
    return exp2f(x);
#endif
}

// ---------------------------------------------------------------------------
// Kernel 1: blocks 0..127 fill lwT4[g*NF+f].j = log2(w(f,4g+j)+eps)
// (coalesced float4 per thread); block 128 computes reg -> out[BATCH].
// ---------------------------------------------------------------------------
#define LW_BLOCKS ((NF * LEN / 4) / 256)   // 128

__global__ __launch_bounds__(256) void lw_reg_kernel(
    const float* __restrict__ t1, const float* __restrict__ t2,
    const float* __restrict__ p1, const float* __restrict__ p2,
    const float* __restrict__ tvt, const float* __restrict__ tvl1,
    const float* __restrict__ tvl2, float4* __restrict__ lwT4,
    float* __restrict__ out) {
    const int bid = blockIdx.x;
    const int tid = threadIdx.x;

    if (bid == LW_BLOCKS) {
        __shared__ float red[256];
        float acc = 0.0f;
        for (int i = tid; i < NC * NF; i += 256) {
            float p = clip01(p1[i]);
            acc += 0.01f * (p * (1.0f - p)) + 0.01f * (p * p);
        }
        if (tid < NC) {
            float p = clip01(p2[tid]);
            acc += 0.01f * (p * (1.0f - p)) + 0.01f * (p * p);
        }
        if (tid < NF) {
            float c = clip01(tvt[tid]);
            acc += 0.01f * (c * (1.0f - c));
        }
        if (tid < NC) {
            float c = clip01(tvl1[tid]);
            acc += 0.01f * (c * (1.0f - c));
        }
        if (tid == 0) {
            float c = clip01(tvl2[0]);
            acc += 0.01f * (c * (1.0f - c));
        }
        red[tid] = acc;
        __syncthreads();
        for (int s = 128; s > 0; s >>= 1) {
            if (tid < s) red[tid] += red[tid + s];
            __syncthreads();
        }
        if (tid == 0) out[BATCH] = red[0];
        return;
    }

    int idx = bid * 256 + tid;          // idx = g*NF + f
    int f = idx & (NF - 1);
    int g = idx >> 6;
    float t1c = fminf(fmaxf(t1[f], 0.0f), (float)(LEN - 1));
    float t2c = fminf(fmaxf(t2[f], 0.0f), (float)(LEN - 1));
    t1c = fminf(t1c, t2c - 1.0f);
    float4 r;
#pragma unroll
    for (int j = 0; j < 4; ++j) {
        float t = (float)(4 * g + j);
        float su = 1.0f / (1.0f + __expf(-BETA * (t - t1c)));
        float sv = 1.0f / (1.0f + __expf(-BETA * (t2c - t)));
        ((float*)&r)[j] = __log2f(su * sv + EPSN);
    }
    lwT4[idx] = r;
}

// ---------------------------------------------------------------------------
// Kernel 2: grid = BATCH (one block per b) x 512 (8 waves, 2 blocks/CU-worth
// of scheduling freedom at 512 grid... grid=256 -> 1 block/CU; TPB=512 keeps
// LDS tiny and leaves headroom). Inner loop in 2-wide vector form so the SLP
// vectorizer can emit v_pk_fma_f32:
//   zpm = pk_fma((A2,-A2), (x,x), (lw,lw));  e=(exp2,exp2);
//   (Sp,Xp) += pk_fma((e0,e0),(1,x));  (Sm,Xm) += pk_fma((e1,e1),(1,x))
// ---------------------------------------------------------------------------
__global__ __launch_bounds__(TPB) void fused_main(
    const float* __restrict__ x, const float4* __restrict__ lwT4,
    const float* __restrict__ av, const float* __restrict__ bv,
    const float* __restrict__ p1, const float* __restrict__ p2,
    const float* __restrict__ tvt_, const float* __restrict__ tvl1_,
    const float* __restrict__ tvl2_, float* __restrict__ out) {
    __shared__ float4 redQ[NQ][NF];      // 8 KB
    __shared__ float r1s[NF];
    __shared__ float r2s[NC];

    const int b = blockIdx.x;
    const int tid = threadIdx.x;
    const int f = tid & (NF - 1);
    const int q = tid >> 6;
    const int ch = f & 1;

    const float B2 = BETA * LOG2E;
    const float KL = KAPPA * LOG2E;
    const float A2 = B2 * av[f];
    const v2f Apm = {A2, -A2};

    const int t0 = q * CHUNK;
    const float4* lw4 = lwT4 + (t0 >> 2) * NF + f;                           // per-lane
    const float4* xp4 = (const float4*)(x + (size_t)b * (LEN * 2) + 2 * t0); // uniform

    v2f SXp0 = {0.f, 0.f}, SXm0 = {0.f, 0.f};
    v2f SXp1 = {0.f, 0.f}, SXm1 = {0.f, 0.f};
#pragma unroll 4
    for (int g = 0; g < CHUNK / 4; ++g) {   // 4 t's per iteration
        float4 lw = lw4[g * NF];
        float4 u0 = xp4[2 * g];             // t = 4g, 4g+1
        float4 u1 = xp4[2 * g + 1];         // t = 4g+2, 4g+3
        float xa = ch ? u0.y : u0.x;
        float xb = ch ? u0.w : u0.z;
        float xc = ch ? u1.y : u1.x;
        float xd = ch ? u1.w : u1.z;
        {
            v2f z = Apm * xa + (v2f){lw.x, lw.x};
            v2f e0 = {fexp2(z.x), fexp2(z.x)};
            v2f e1 = {fexp2(z.y), fexp2(z.y)};
            v2f m = {1.0f, xa};
            SXp0 += e0 * m;
            SXm0 += e1 * m;
        }
        {
            v2f z = Apm * xb + (v2f){lw.y, lw.y};
            v2f e0 = {fexp2(z.x), fexp2(z.x)};
            v2f e1 = {fexp2(z.y), fexp2(z.y)};
            v2f m = {1.0f, xb};
            SXp1 += e0 * m;
            SXm1 += e1 * m;
        }
        {
            v2f z = Apm * xc + (v2f){lw.z, lw.z};
            v2f e0 = {fexp2(z.x), fexp2(z.x)};
            v2f e1 = {fexp2(z.y), fexp2(z.y)};
            v2f m = {1.0f, xc};
            SXp0 += e0 * m;
            SXm0 += e1 * m;
        }
        {
            v2f z = Apm * xd + (v2f){lw.w, lw.w};
            v2f e0 = {fexp2(z.x), fexp2(z.x)};
            v2f e1 = {fexp2(z.y), fexp2(z.y)};
            v2f m = {1.0f, xd};
            SXp1 += e0 * m;
            SXm1 += e1 * m;
        }
    }
    v2f SXp = SXp0 + SXp1;
    v2f SXm = SXm0 + SXm1;

    redQ[q][f] = make_float4(SXp.x, SXp.y, SXm.x, SXm.y);
    __syncthreads();
    if (tid >= 64) return;

    // ---- finish: single wave (validated R5-R7) ----
    const int l = tid;
    float ax = 0.f, ay = 0.f, az = 0.f, aw = 0.f;
#pragma unroll
    for (int s = 0; s < NQ; ++s) {
        float4 v = redQ[s][l];
        ax += v.x; ay += v.y; az += v.z; aw += v.w;
    }
    {
        float af = av[l], bf = bv[l];
        float tvt = clip01(tvt_[l]);
        float rmax = af * (ay / ax);
        float rmin = af * (aw / az);
        r1s[l] = tvt * rmax + (1.0f - tvt) * rmin - bf;
    }

    // stage 2: lane l -> clause c = l&15, f-quarter j = l>>4
    {
        const int c = l & 15;
        const int j = l >> 4;
        float so = 0.f, wo = 0.f, sa = 0.f, wa = 0.f;
#pragma unroll
        for (int i = 0; i < 16; ++i) {
            int ff = j * 16 + i;
            float r1v = r1s[ff];
            float lg = __log2f(clip01(p1[c * NF + ff]) + EPSN);
            float z = KL * r1v;
            float eo = fexp2(z + lg);
            float ea = fexp2(lg - z);
            so += eo; wo = fmaf(eo, r1v, wo);
            sa += ea; wa = fmaf(ea, r1v, wa);
        }
#pragma unroll
        for (int d = 16; d < 64; d <<= 1) {
            so += __shfl_xor(so, d);
            wo += __shfl_xor(wo, d);
            sa += __shfl_xor(sa, d);
            wa += __shfl_xor(wa, d);
        }
        if (l < NC) {
            float tvl1 = clip01(tvl1_[l]);
            r2s[l] = tvl1 * (wo / so) + (1.0f - tvl1) * (wa / sa);
        }
    }

    // stage 3: lane 0
    if (l == 0) {
        float so = 0.f, wo = 0.f, sa = 0.f, wa = 0.f;
#pragma unroll
        for (int c = 0; c < NC; ++c) {
            float lg = __log2f(clip01(p2[c]) + EPSN);
            float r2v = r2s[c];
            float z = KL * r2v;
            float eo = fexp2(z + lg);
            float ea = fexp2(lg - z);
            so += eo; wo = fmaf(eo, r2v, wo);
            sa += ea; wa = fmaf(ea, r2v, wa);
        }
        float tvl2 = clip01(tvl2_[0]);
        out[b] = tvl2 * (wo / so) + (1.0f - tvl2) * (wa / sa);
    }
}

// ---------------------------------------------------------------------------
// Fallback: R6's validated single kernel (inline w), used when ws too small.
// ---------------------------------------------------------------------------
__device__ __forceinline__ float frcp(float x) {
#if __has_builtin(__builtin_amdgcn_rcpf)
    return __builtin_amdgcn_rcpf(x);
#else
    return 1.0f / x;
#endif
}

__global__ __launch_bounds__(TPB) void fused_inline(
    const float* __restrict__ x, const float* __restrict__ t1g,
    const float* __restrict__ t2g, const float* __restrict__ av,
    const float* __restrict__ bv, const float* __restrict__ p1,
    const float* __restrict__ p2, const float* __restrict__ tvt_,
    const float* __restrict__ tvl1_, const float* __restrict__ tvl2_,
    float* __restrict__ out) {
    __shared__ float4 redQ[NQ][NF];
    __shared__ float r1s[NF];
    __shared__ float r2s[NC];

    const int b = blockIdx.x;
    const int tid = threadIdx.x;
    const int f = tid & (NF - 1);
    const int q = tid >> 6;
    const int ch = f & 1;

    const float B2 = BETA * LOG2E;
    const float KL = KAPPA * LOG2E;
    const float A2 = B2 * av[f];

    float t1c = fminf(fmaxf(t1g[f], 0.0f), (float)(LEN - 1));
    float t2c = fminf(fmaxf(t2g[f], 0.0f), (float)(LEN - 1));
    t1c = fminf(t1c, t2c - 1.0f);
    const float c1 = B2 * t1c;
    const float c2 = -B2 * t2c;

    const int t0 = q * CHUNK;
    const float4* xp4 = (const float4*)(x + (size_t)b * (LEN * 2) + 2 * t0);

    float Sp = 0.f, Xp = 0.f, Sm = 0.f, Xm = 0.f;
#pragma unroll 4
    for (int k2 = 0; k2 < CHUNK / 2; ++k2) {
        float4 v = xp4[k2];
        float xa = ch ? v.y : v.x;
        float xb = ch ? v.w : v.z;
        float tfa = (float)(t0 + 2 * k2);
        float tfb = tfa + 1.0f;
        {
            float g1 = fmaf(-B2, tfa, c1);
            float g2 = fmaf(B2, tfa, c2);
            float den = (1.0f + fexp2(g1)) * (1.0f + fexp2(g2));
            float w = frcp(den);
            float P = fexp2(A2 * xa);
            float Pm = frcp(P);
            float tp = P * w, tm = Pm * w;
            Sp += tp; Xp = fmaf(tp, xa, Xp);
            Sm += tm; Xm = fmaf(tm, xa, Xm);
        }
        {
            float g1 = fmaf(-B2, tfb, c1);
            float g2 = fmaf(B2, tfb, c2);
            float den = (1.0f + fexp2(g1)) * (1.0f + fexp2(g2));
            float w = frcp(den);
            float P = fexp2(A2 * xb);
            float Pm = frcp(P);
            float tp = P * w, tm = Pm * w;
            Sp += tp; Xp = fmaf(tp, xb, Xp);
            Sm += tm; Xm = fmaf(tm, xb, Xm);
        }
    }

    redQ[q][f] = make_float4(Sp, Xp, Sm, Xm);

    if (b == 0 && q == NQ - 1) {
        const int l = f;
        float acc = 0.0f;
#pragma unroll
        for (int i = 0; i < 16; ++i) {
            float p = clip01(p1[i * NF + l]);
            acc += 0.01f * (p * (1.0f - p)) + 0.01f * (p * p);
        }
        {
            float c = clip01(tvt_[l]);
            acc += 0.01f * (c * (1.0f - c));
        }
        if (l < NC) {
            float p = clip01(p2[l]);
            acc += 0.01f * (p * (1.0f - p)) + 0.01f * (p * p);
            float c = clip01(tvl1_[l]);
            acc += 0.01f * (c * (1.0f - c));
        }
        if (l == 0) {
            float c = clip01(tvl2_[0]);
            acc += 0.01f * (c * (1.0f - c));
        }
#pragma unroll
        for (int d = 1; d < 64; d <<= 1) acc += __shfl_xor(acc, d);
        if (l == 0) out[BATCH] = acc;
    }

    __syncthreads();
    if (tid >= 64) return;

    const int l = tid;
    float ax = 0.f, ay = 0.f, az = 0.f, aw = 0.f;
#pragma unroll
    for (int s = 0; s < NQ; ++s) {
        float4 v = redQ[s][l];
        ax += v.x; ay += v.y; az += v.z; aw += v.w;
    }
    {
        float af = av[l], bf = bv[l];
        float tvt = clip01(tvt_[l]);
        float rmax = af * (ay / ax);
        float rmin = af * (aw / az);
        r1s[l] = tvt * rmax + (1.0f - tvt) * rmin - bf;
    }
    {
        const int c = l & 15;
        const int j = l >> 4;
        float so = 0.f, wo = 0.f, sa = 0.f, wa = 0.f;
#pragma unroll
        for (int i = 0; i < 16; ++i) {
            int ff = j * 16 + i;
            float r1v = r1s[ff];
            float lg = __log2f(clip01(p1[c * NF + ff]) + EPSN);
            float z = KL * r1v;
            float eo = fexp2(z + lg);
            float ea = fexp2(lg - z);
            so += eo; wo = fmaf(eo, r1v, wo);
            sa += ea; wa = fmaf(ea, r1v, wa);
        }
#pragma unroll
        for (int d = 16; d < 64; d <<= 1) {
            so += __shfl_xor(so, d);
            wo += __shfl_xor(wo, d);
            sa += __shfl_xor(sa, d);
            wa += __shfl_xor(wa, d);
        }
        if (l < NC) {
            float tvl1 = clip01(tvl1_[l]);
            r2s[l] = tvl1 * (wo / so) + (1.0f - tvl1) * (wa / sa);
        }
    }
    if (l == 0) {
        float so = 0.f, wo = 0.f, sa = 0.f, wa = 0.f;
#pragma unroll
        for (int c = 0; c < NC; ++c) {
            float lg = __log2f(clip01(p2[c]) + EPSN);
            float r2v = r2s[c];
            float z = KL * r2v;
            float eo = fexp2(z + lg);
            float ea = fexp2(lg - z);
            so += eo; wo = fmaf(eo, r2v, wo);
            sa += ea; wa = fmaf(ea, r2v, wa);
        }
        float tvl2 = clip01(tvl2_[0]);
        out[b] = tvl2 * (wo / so) + (1.0f - tvl2) * (wa / sa);
    }
}

// ---------------------------------------------------------------------------
extern "C" void kernel_launch(void* const* d_in, const int* in_sizes, int n_in,
                              void* d_out, int out_size, void* d_ws, size_t ws_size,
                              hipStream_t stream) {
    const float* x    = (const float*)d_in[0];
    const float* t1   = (const float*)d_in[1];
    const float* t2   = (const float*)d_in[2];
    const float* a    = (const float*)d_in[3];
    const float* bv   = (const float*)d_in[4];
    const float* p1   = (const float*)d_in[5];
    const float* p2   = (const float*)d_in[6];
    const float* tvt  = (const float*)d_in[7];
    const float* tvl1 = (const float*)d_in[8];
    const float* tvl2 = (const float*)d_in[9];
    float* out = (float*)d_out;

    const size_t lw_bytes = (size_t)(NF * LEN) * sizeof(float);   // 512 KB

    if (d_ws && ws_size >= lw_bytes) {
        float4* lwT4 = (float4*)d_ws;
        lw_reg_kernel<<<LW_BLOCKS + 1, 256, 0, stream>>>(t1, t2, p1, p2, tvt, tvl1,
                                                         tvl2, lwT4, out);
        fused_main<<<BATCH, TPB, 0, stream>>>(x, lwT4, a, bv, p1, p2,
                                              tvt, tvl1, tvl2, out);
    } else {
        fused_inline<<<BATCH, TPB, 0, stream>>>(x, t1, t2, a, bv, p1, p2,
                                                tvt, tvl1, tvl2, out);
    }
}

// Round 9
// 26.650 us; speedup vs baseline: 1.0112x; 1.0112x over previous
//
#include <hip/hip_runtime.h>
#include <math.h>

#define NF 64
#define NC 16
#define LEN 2048
#define BATCH 256
#define BETA 2.5f
#define KAPPA 10.0f
#define EPSN 1e-12f
#define LOG2E 1.4426950408889634f

#define TPB 1024            // 16 waves per block, one block per batch element

// fallback (inline-w single kernel) config
#define FBQ (TPB / NF)      // 16 waves
#define FBCHUNK (LEN / FBQ) // 128 t's per thread

__device__ __forceinline__ float clip01(float v) { return fminf(fmaxf(v, 0.0f), 1.0f); }

__device__ __forceinline__ float fexp2(float x) {
#if __has_builtin(__builtin_amdgcn_exp2f)
    return __builtin_amdgcn_exp2f(x);
#else
    return exp2f(x);
#endif
}

__device__ __forceinline__ float frcp(float x) {
#if __has_builtin(__builtin_amdgcn_rcpf)
    return __builtin_amdgcn_rcpf(x);
#else
    return 1.0f / x;
#endif
}

// ---------------------------------------------------------------------------
// Kernel 1: blocks 0..127 fill the f-major table
//   lwF4[f*(LEN/4) + g].j = log2(w(f, 4g+j) + eps)
// (per-lane coalesced along t for the main kernel); block 128: reg -> out[BATCH].
// ---------------------------------------------------------------------------
#define LW_BLOCKS ((NF * LEN / 4) / 256)   // 128

__global__ __launch_bounds__(256) void lw_reg_kernel(
    const float* __restrict__ t1, const float* __restrict__ t2,
    const float* __restrict__ p1, const float* __restrict__ p2,
    const float* __restrict__ tvt, const float* __restrict__ tvl1,
    const float* __restrict__ tvl2, float4* __restrict__ lwF4,
    float* __restrict__ out) {
    const int bid = blockIdx.x;
    const int tid = threadIdx.x;

    if (bid == LW_BLOCKS) {
        __shared__ float red[256];
        float acc = 0.0f;
        for (int i = tid; i < NC * NF; i += 256) {
            float p = clip01(p1[i]);
            acc += 0.01f * (p * (1.0f - p)) + 0.01f * (p * p);
        }
        if (tid < NC) {
            float p = clip01(p2[tid]);
            acc += 0.01f * (p * (1.0f - p)) + 0.01f * (p * p);
        }
        if (tid < NF) {
            float c = clip01(tvt[tid]);
            acc += 0.01f * (c * (1.0f - c));
        }
        if (tid < NC) {
            float c = clip01(tvl1[tid]);
            acc += 0.01f * (c * (1.0f - c));
        }
        if (tid == 0) {
            float c = clip01(tvl2[0]);
            acc += 0.01f * (c * (1.0f - c));
        }
        red[tid] = acc;
        __syncthreads();
        for (int s = 128; s > 0; s >>= 1) {
            if (tid < s) red[tid] += red[tid + s];
            __syncthreads();
        }
        if (tid == 0) out[BATCH] = red[0];
        return;
    }

    int idx = bid * 256 + tid;          // idx = f*(LEN/4) + g
    int f = idx >> 9;                   // LEN/4 = 512 groups per feature
    int g = idx & 511;
    float t1c = fminf(fmaxf(t1[f], 0.0f), (float)(LEN - 1));
    float t2c = fminf(fmaxf(t2[f], 0.0f), (float)(LEN - 1));
    t1c = fminf(t1c, t2c - 1.0f);
    float4 r;
#pragma unroll
    for (int j = 0; j < 4; ++j) {
        float t = (float)(4 * g + j);
        float su = 1.0f / (1.0f + __expf(-BETA * (t - t1c)));
        float sv = 1.0f / (1.0f + __expf(-BETA * (t2c - t)));
        ((float*)&r)[j] = __log2f(su * sv + EPSN);
    }
    lwF4[idx] = r;
}

// ---------------------------------------------------------------------------
// Kernel 2: grid = BATCH x 1024. Wave = one feature, lanes = t (lane l covers
// t = T + 4l, 256 t's per trip). Only the window [t1c-16, t2c+17] is swept:
// outside it w <= e^{-40}, skipped mass <= ~3e-9 relative (threshold 0.107).
// Dynamic f assignment via LDS atomic balances variable window sizes.
// Per-f partial reduced with 6-step shfl_xor -> r1s[f]; one barrier; wave 0
// runs the validated finish (stage2 4 lanes/clause + shfl; stage3).
// reg scalar: block 0, wave 1.
// ---------------------------------------------------------------------------
__global__ __launch_bounds__(TPB) void fused_main(
    const float* __restrict__ x, const float4* __restrict__ lwF4,
    const float* __restrict__ t1g, const float* __restrict__ t2g,
    const float* __restrict__ av, const float* __restrict__ bv,
    const float* __restrict__ p1, const float* __restrict__ p2,
    const float* __restrict__ tvt_, const float* __restrict__ tvl1_,
    const float* __restrict__ tvl2_, float* __restrict__ out) {
    __shared__ int fcnt;
    __shared__ float r1s[NF];
    __shared__ float r2s[NC];

    const int b = blockIdx.x;
    const int tid = threadIdx.x;
    const int l = tid & 63;

    const float B2 = BETA * LOG2E;
    const float KL = KAPPA * LOG2E;

    if (tid == 0) fcnt = 0;
    __syncthreads();

    const float4* xb4 = (const float4*)(x + (size_t)b * (LEN * 2));

    for (;;) {
        int f;
        if (l == 0) f = atomicAdd(&fcnt, 1);
        f = __shfl(f, 0);
        if (f >= NF) break;

        float t1c = fminf(fmaxf(t1g[f], 0.0f), (float)(LEN - 1));
        float t2c = fminf(fmaxf(t2g[f], 0.0f), (float)(LEN - 1));
        t1c = fminf(t1c, t2c - 1.0f);
        int lo = (int)t1c - 16; lo = (lo < 0 ? 0 : lo) & ~3;
        int hi = (int)t2c + 18; hi = (hi > LEN ? LEN : hi);

        const float A2 = B2 * av[f];
        const int ch = f & 1;
        const float4* lwf = lwF4 + f * (LEN / 4);

        float Sp = 0.f, Xp = 0.f, Sm = 0.f, Xm = 0.f;
        for (int T = lo; T < hi; T += 256) {
            int t = T + 4 * l;
            if (t < LEN) {
                float4 lw = lwf[t >> 2];
                float4 u0 = xb4[t >> 1];          // x[t][0..1], x[t+1][0..1]
                float4 u1 = xb4[(t >> 1) + 1];    // x[t+2][0..1], x[t+3][0..1]
                float xa = ch ? u0.y : u0.x;
                float xb_ = ch ? u0.w : u0.z;
                float xc = ch ? u1.y : u1.x;
                float xd = ch ? u1.w : u1.z;
                float e;
                e = fexp2(fmaf(A2, xa, lw.x));   Sp += e; Xp = fmaf(e, xa, Xp);
                e = fexp2(fmaf(-A2, xa, lw.x));  Sm += e; Xm = fmaf(e, xa, Xm);
                e = fexp2(fmaf(A2, xb_, lw.y));  Sp += e; Xp = fmaf(e, xb_, Xp);
                e = fexp2(fmaf(-A2, xb_, lw.y)); Sm += e; Xm = fmaf(e, xb_, Xm);
                e = fexp2(fmaf(A2, xc, lw.z));   Sp += e; Xp = fmaf(e, xc, Xp);
                e = fexp2(fmaf(-A2, xc, lw.z));  Sm += e; Xm = fmaf(e, xc, Xm);
                e = fexp2(fmaf(A2, xd, lw.w));   Sp += e; Xp = fmaf(e, xd, Xp);
                e = fexp2(fmaf(-A2, xd, lw.w));  Sm += e; Xm = fmaf(e, xd, Xm);
            }
        }
#pragma unroll
        for (int d = 1; d < 64; d <<= 1) {
            Sp += __shfl_xor(Sp, d);
            Xp += __shfl_xor(Xp, d);
            Sm += __shfl_xor(Sm, d);
            Xm += __shfl_xor(Xm, d);
        }
        if (l == 0) {
            float af = av[f], bf = bv[f];
            float tvt = clip01(tvt_[f]);
            r1s[f] = tvt * (af * (Xp / Sp)) + (1.0f - tvt) * (af * (Xm / Sm)) - bf;
        }
    }

    __syncthreads();

    // ---- reg scalar: block 0, wave 1 (runs alongside wave 0's finish) ----
    if (b == 0 && tid >= 64 && tid < 128) {
        float acc = 0.0f;
#pragma unroll
        for (int i = 0; i < 16; ++i) {
            float p = clip01(p1[i * NF + l]);
            acc += 0.01f * (p * (1.0f - p)) + 0.01f * (p * p);
        }
        {
            float c = clip01(tvt_[l]);
            acc += 0.01f * (c * (1.0f - c));
        }
        if (l < NC) {
            float p = clip01(p2[l]);
            acc += 0.01f * (p * (1.0f - p)) + 0.01f * (p * p);
            float c = clip01(tvl1_[l]);
            acc += 0.01f * (c * (1.0f - c));
        }
        if (l == 0) {
            float c = clip01(tvl2_[0]);
            acc += 0.01f * (c * (1.0f - c));
        }
#pragma unroll
        for (int d = 1; d < 64; d <<= 1) acc += __shfl_xor(acc, d);
        if (l == 0) out[BATCH] = acc;
    }

    if (tid >= 64) return;

    // ---- finish: single wave (validated R5-R8), r1s from LDS ----
    // stage 2: lane l -> clause c = l&15, f-quarter j = l>>4
    {
        const int c = l & 15;
        const int j = l >> 4;
        float so = 0.f, wo = 0.f, sa = 0.f, wa = 0.f;
#pragma unroll
        for (int i = 0; i < 16; ++i) {
            int ff = j * 16 + i;
            float r1v = r1s[ff];
            float lg = __log2f(clip01(p1[c * NF + ff]) + EPSN);
            float z = KL * r1v;
            float eo = fexp2(z + lg);
            float ea = fexp2(lg - z);
            so += eo; wo = fmaf(eo, r1v, wo);
            sa += ea; wa = fmaf(ea, r1v, wa);
        }
#pragma unroll
        for (int d = 16; d < 64; d <<= 1) {
            so += __shfl_xor(so, d);
            wo += __shfl_xor(wo, d);
            sa += __shfl_xor(sa, d);
            wa += __shfl_xor(wa, d);
        }
        if (l < NC) {
            float tvl1 = clip01(tvl1_[l]);
            r2s[l] = tvl1 * (wo / so) + (1.0f - tvl1) * (wa / sa);
        }
    }

    // stage 3: lane 0
    if (l == 0) {
        float so = 0.f, wo = 0.f, sa = 0.f, wa = 0.f;
#pragma unroll
        for (int c = 0; c < NC; ++c) {
            float lg = __log2f(clip01(p2[c]) + EPSN);
            float r2v = r2s[c];
            float z = KL * r2v;
            float eo = fexp2(z + lg);
            float ea = fexp2(lg - z);
            so += eo; wo = fmaf(eo, r2v, wo);
            sa += ea; wa = fmaf(ea, r2v, wa);
        }
        float tvl2 = clip01(tvl2_[0]);
        out[b] = tvl2 * (wo / so) + (1.0f - tvl2) * (wa / sa);
    }
}

// ---------------------------------------------------------------------------
// Fallback: R6/R7's validated single kernel (inline w), used when ws too small.
// ---------------------------------------------------------------------------
__global__ __launch_bounds__(TPB) void fused_inline(
    const float* __restrict__ x, const float* __restrict__ t1g,
    const float* __restrict__ t2g, const float* __restrict__ av,
    const float* __restrict__ bv, const float* __restrict__ p1,
    const float* __restrict__ p2, const float* __restrict__ tvt_,
    const float* __restrict__ tvl1_, const float* __restrict__ tvl2_,
    float* __restrict__ out) {
    __shared__ float4 redQ[FBQ][NF];
    __shared__ float r1s[NF];
    __shared__ float r2s[NC];

    const int b = blockIdx.x;
    const int tid = threadIdx.x;
    const int f = tid & (NF - 1);
    const int q = tid >> 6;
    const int ch = f & 1;

    const float B2 = BETA * LOG2E;
    const float KL = KAPPA * LOG2E;
    const float A2 = B2 * av[f];

    float t1c = fminf(fmaxf(t1g[f], 0.0f), (float)(LEN - 1));
    float t2c = fminf(fmaxf(t2g[f], 0.0f), (float)(LEN - 1));
    t1c = fminf(t1c, t2c - 1.0f);
    const float c1 = B2 * t1c;
    const float c2 = -B2 * t2c;

    const int t0 = q * FBCHUNK;
    const float4* xp4 = (const float4*)(x + (size_t)b * (LEN * 2) + 2 * t0);

    float Sp = 0.f, Xp = 0.f, Sm = 0.f, Xm = 0.f;
#pragma unroll 4
    for (int k2 = 0; k2 < FBCHUNK / 2; ++k2) {
        float4 v = xp4[k2];
        float xa = ch ? v.y : v.x;
        float xb = ch ? v.w : v.z;
        float tfa = (float)(t0 + 2 * k2);
        float tfb = tfa + 1.0f;
        {
            float g1 = fmaf(-B2, tfa, c1);
            float g2 = fmaf(B2, tfa, c2);
            float den = (1.0f + fexp2(g1)) * (1.0f + fexp2(g2));
            float w = frcp(den);
            float P = fexp2(A2 * xa);
            float Pm = frcp(P);
            float tp = P * w, tm = Pm * w;
            Sp += tp; Xp = fmaf(tp, xa, Xp);
            Sm += tm; Xm = fmaf(tm, xa, Xm);
        }
        {
            float g1 = fmaf(-B2, tfb, c1);
            float g2 = fmaf(B2, tfb, c2);
            float den = (1.0f + fexp2(g1)) * (1.0f + fexp2(g2));
            float w = frcp(den);
            float P = fexp2(A2 * xb);
            float Pm = frcp(P);
            float tp = P * w, tm = Pm * w;
            Sp += tp; Xp = fmaf(tp, xb, Xp);
            Sm += tm; Xm = fmaf(tm, xb, Xm);
        }
    }

    redQ[q][f] = make_float4(Sp, Xp, Sm, Xm);

    if (b == 0 && q == FBQ - 1) {
        const int l = f;
        float acc = 0.0f;
#pragma unroll
        for (int i = 0; i < 16; ++i) {
            float p = clip01(p1[i * NF + l]);
            acc += 0.01f * (p * (1.0f - p)) + 0.01f * (p * p);
        }
        {
            float c = clip01(tvt_[l]);
            acc += 0.01f * (c * (1.0f - c));
        }
        if (l < NC) {
            float p = clip01(p2[l]);
            acc += 0.01f * (p * (1.0f - p)) + 0.01f * (p * p);
            float c = clip01(tvl1_[l]);
            acc += 0.01f * (c * (1.0f - c));
        }
        if (l == 0) {
            float c = clip01(tvl2_[0]);
            acc += 0.01f * (c * (1.0f - c));
        }
#pragma unroll
        for (int d = 1; d < 64; d <<= 1) acc += __shfl_xor(acc, d);
        if (l == 0) out[BATCH] = acc;
    }

    __syncthreads();
    if (tid >= 64) return;

    const int l = tid;
    float ax = 0.f, ay = 0.f, az = 0.f, aw = 0.f;
#pragma unroll
    for (int s = 0; s < FBQ; ++s) {
        float4 v = redQ[s][l];
        ax += v.x; ay += v.y; az += v.z; aw += v.w;
    }
    {
        float af = av[l], bf = bv[l];
        float tvt = clip01(tvt_[l]);
        float rmax = af * (ay / ax);
        float rmin = af * (aw / az);
        r1s[l] = tvt * rmax + (1.0f - tvt) * rmin - bf;
    }
    {
        const int c = l & 15;
        const int j = l >> 4;
        float so = 0.f, wo = 0.f, sa = 0.f, wa = 0.f;
#pragma unroll
        for (int i = 0; i < 16; ++i) {
            int ff = j * 16 + i;
            float r1v = r1s[ff];
            float lg = __log2f(clip01(p1[c * NF + ff]) + EPSN);
            float z = KL * r1v;
            float eo = fexp2(z + lg);
            float ea = fexp2(lg - z);
            so += eo; wo = fmaf(eo, r1v, wo);
            sa += ea; wa = fmaf(ea, r1v, wa);
        }
#pragma unroll
        for (int d = 16; d < 64; d <<= 1) {
            so += __shfl_xor(so, d);
            wo += __shfl_xor(wo, d);
            sa += __shfl_xor(sa, d);
            wa += __shfl_xor(wa, d);
        }
        if (l < NC) {
            float tvl1 = clip01(tvl1_[l]);
            r2s[l] = tvl1 * (wo / so) + (1.0f - tvl1) * (wa / sa);
        }
    }
    if (l == 0) {
        float so = 0.f, wo = 0.f, sa = 0.f, wa = 0.f;
#pragma unroll
        for (int c = 0; c < NC; ++c) {
            float lg = __log2f(clip01(p2[c]) + EPSN);
            float r2v = r2s[c];
            float z = KL * r2v;
            float eo = fexp2(z + lg);
            float ea = fexp2(lg - z);
            so += eo; wo = fmaf(eo, r2v, wo);
            sa += ea; wa = fmaf(ea, r2v, wa);
        }
        float tvl2 = clip01(tvl2_[0]);
        out[b] = tvl2 * (wo / so) + (1.0f - tvl2) * (wa / sa);
    }
}

// ---------------------------------------------------------------------------
extern "C" void kernel_launch(void* const* d_in, const int* in_sizes, int n_in,
                              void* d_out, int out_size, void* d_ws, size_t ws_size,
                              hipStream_t stream) {
    const float* x    = (const float*)d_in[0];
    const float* t1   = (const float*)d_in[1];
    const float* t2   = (const float*)d_in[2];
    const float* a    = (const float*)d_in[3];
    const float* bv   = (const float*)d_in[4];
    const float* p1   = (const float*)d_in[5];
    const float* p2   = (const float*)d_in[6];
    const float* tvt  = (const float*)d_in[7];
    const float* tvl1 = (const float*)d_in[8];
    const float* tvl2 = (const float*)d_in[9];
    float* out = (float*)d_out;

    const size_t lw_bytes = (size_t)(NF * LEN) * sizeof(float);   // 512 KB

    if (d_ws && ws_size >= lw_bytes) {
        float4* lwF4 = (float4*)d_ws;
        lw_reg_kernel<<<LW_BLOCKS + 1, 256, 0, stream>>>(t1, t2, p1, p2, tvt, tvl1,
                                                         tvl2, lwF4, out);
        fused_main<<<BATCH, TPB, 0, stream>>>(x, lwF4, t1, t2, a, bv, p1, p2,
                                              tvt, tvl1, tvl2, out);
    } else {
        fused_inline<<<BATCH, TPB, 0, stream>>>(x, t1, t2, a, bv, p1, p2,
                                                tvt, tvl1, tvl2, out);
    }
}

// Round 10
// 25.994 us; speedup vs baseline: 1.0368x; 1.0252x over previous
//
#include <hip/hip_runtime.h>
#include <math.h>

#define NF 64
#define NC 16
#define LEN 2048
#define BATCH 256
#define BETA 2.5f
#define KAPPA 10.0f
#define EPSN 1e-12f
#define LOG2E 1.4426950408889634f

#define TPB 1024
#define NQ (TPB / NF)        // 16 waves per block
#define CHUNK (LEN / NQ)     // 128 t's per thread

__device__ __forceinline__ float clip01(float v) { return fminf(fmaxf(v, 0.0f), 1.0f); }

__device__ __forceinline__ float fexp2(float x) {
#if __has_builtin(__builtin_amdgcn_exp2f)
    return __builtin_amdgcn_exp2f(x);
#else
    return exp2f(x);
#endif
}

__device__ __forceinline__ float frcp(float x) {
#if __has_builtin(__builtin_amdgcn_rcpf)
    return __builtin_amdgcn_rcpf(x);
#else
    return 1.0f / x;
#endif
}

// ---------------------------------------------------------------------------
// Kernel 1: blocks 0..127 fill lwT4[g*NF+f].j = log2(w(f,4g+j)+eps)
// (coalesced float4 per thread); block 128 computes reg -> out[BATCH].
// ---------------------------------------------------------------------------
#define LW_BLOCKS ((NF * LEN / 4) / 256)   // 128

__global__ __launch_bounds__(256) void lw_reg_kernel(
    const float* __restrict__ t1, const float* __restrict__ t2,
    const float* __restrict__ p1, const float* __restrict__ p2,
    const float* __restrict__ tvt, const float* __restrict__ tvl1,
    const float* __restrict__ tvl2, float4* __restrict__ lwT4,
    float* __restrict__ out) {
    const int bid = blockIdx.x;
    const int tid = threadIdx.x;

    if (bid == LW_BLOCKS) {
        __shared__ float red[256];
        float acc = 0.0f;
        for (int i = tid; i < NC * NF; i += 256) {
            float p = clip01(p1[i]);
            acc += 0.01f * (p * (1.0f - p)) + 0.01f * (p * p);
        }
        if (tid < NC) {
            float p = clip01(p2[tid]);
            acc += 0.01f * (p * (1.0f - p)) + 0.01f * (p * p);
        }
        if (tid < NF) {
            float c = clip01(tvt[tid]);
            acc += 0.01f * (c * (1.0f - c));
        }
        if (tid < NC) {
            float c = clip01(tvl1[tid]);
            acc += 0.01f * (c * (1.0f - c));
        }
        if (tid == 0) {
            float c = clip01(tvl2[0]);
            acc += 0.01f * (c * (1.0f - c));
        }
        red[tid] = acc;
        __syncthreads();
        for (int s = 128; s > 0; s >>= 1) {
            if (tid < s) red[tid] += red[tid + s];
            __syncthreads();
        }
        if (tid == 0) out[BATCH] = red[0];
        return;
    }

    int idx = bid * 256 + tid;          // idx = g*NF + f
    int f = idx & (NF - 1);
    int g = idx >> 6;
    float t1c = fminf(fmaxf(t1[f], 0.0f), (float)(LEN - 1));
    float t2c = fminf(fmaxf(t2[f], 0.0f), (float)(LEN - 1));
    t1c = fminf(t1c, t2c - 1.0f);
    float4 r;
#pragma unroll
    for (int j = 0; j < 4; ++j) {
        float t = (float)(4 * g + j);
        float su = 1.0f / (1.0f + __expf(-BETA * (t - t1c)));
        float sv = 1.0f / (1.0f + __expf(-BETA * (t2c - t)));
        ((float*)&r)[j] = __log2f(su * sv + EPSN);
    }
    lwT4[idx] = r;
}

// ---------------------------------------------------------------------------
// Kernel 2: grid = BATCH x 1024 (16 waves), one block per batch element.
// stage1 inner loop: 2 exp2/element via the log2-domain table,
//   weights w*2^{+-A2*x} (b folded out; r = a*X/S - b recovered in finish).
// Per-wave partial -> LDS; one barrier; wave 0 runs the validated finish.
// ---------------------------------------------------------------------------
__global__ __launch_bounds__(TPB) void fused_main(
    const float* __restrict__ x, const float4* __restrict__ lwT4,
    const float* __restrict__ av, const float* __restrict__ bv,
    const float* __restrict__ p1, const float* __restrict__ p2,
    const float* __restrict__ tvt_, const float* __restrict__ tvl1_,
    const float* __restrict__ tvl2_, float* __restrict__ out) {
    __shared__ float4 redQ[NQ][NF];      // 16 KB
    __shared__ float r1s[NF];
    __shared__ float r2s[NC];

    const int b = blockIdx.x;
    const int tid = threadIdx.x;
    const int f = tid & (NF - 1);
    const int q = tid >> 6;
    const int ch = f & 1;

    const float B2 = BETA * LOG2E;
    const float KL = KAPPA * LOG2E;
    const float A2 = B2 * av[f];

    const int t0 = q * CHUNK;
    const float4* lw4 = lwT4 + (t0 >> 2) * NF + f;                     // per-lane
    const float4* xp4 = (const float4*)(x + (size_t)b * (LEN * 2) + 2 * t0); // uniform

    float Sp0 = 0.f, Xp0 = 0.f, Sm0 = 0.f, Xm0 = 0.f;
    float Sp1 = 0.f, Xp1 = 0.f, Sm1 = 0.f, Xm1 = 0.f;
#pragma unroll 4
    for (int g = 0; g < CHUNK / 4; ++g) {   // 4 t's per iteration
        float4 lw = lw4[g * NF];
        float4 u0 = xp4[2 * g];             // t = 4g, 4g+1
        float4 u1 = xp4[2 * g + 1];         // t = 4g+2, 4g+3
        float xa = ch ? u0.y : u0.x;
        float xb = ch ? u0.w : u0.z;
        float xc = ch ? u1.y : u1.x;
        float xd = ch ? u1.w : u1.z;
        float e;
        e = fexp2(fmaf(A2, xa, lw.x));  Sp0 += e; Xp0 = fmaf(e, xa, Xp0);
        e = fexp2(fmaf(-A2, xa, lw.x)); Sm0 += e; Xm0 = fmaf(e, xa, Xm0);
        e = fexp2(fmaf(A2, xb, lw.y));  Sp1 += e; Xp1 = fmaf(e, xb, Xp1);
        e = fexp2(fmaf(-A2, xb, lw.y)); Sm1 += e; Xm1 = fmaf(e, xb, Xm1);
        e = fexp2(fmaf(A2, xc, lw.z));  Sp0 += e; Xp0 = fmaf(e, xc, Xp0);
        e = fexp2(fmaf(-A2, xc, lw.z)); Sm0 += e; Xm0 = fmaf(e, xc, Xm0);
        e = fexp2(fmaf(A2, xd, lw.w));  Sp1 += e; Xp1 = fmaf(e, xd, Xp1);
        e = fexp2(fmaf(-A2, xd, lw.w)); Sm1 += e; Xm1 = fmaf(e, xd, Xm1);
    }

    redQ[q][f] = make_float4(Sp0 + Sp1, Xp0 + Xp1, Sm0 + Sm1, Xm0 + Xm1);
    __syncthreads();
    if (tid >= 64) return;

    // ---- finish: single wave (validated R5-R9) ----
    const int l = tid;
    float ax = 0.f, ay = 0.f, az = 0.f, aw = 0.f;
#pragma unroll
    for (int s = 0; s < NQ; ++s) {
        float4 v = redQ[s][l];
        ax += v.x; ay += v.y; az += v.z; aw += v.w;
    }
    {
        float af = av[l], bf = bv[l];
        float tvt = clip01(tvt_[l]);
        float rmax = af * (ay / ax);
        float rmin = af * (aw / az);
        r1s[l] = tvt * rmax + (1.0f - tvt) * rmin - bf;
    }

    // stage 2: lane l -> clause c = l&15, f-quarter j = l>>4
    {
        const int c = l & 15;
        const int j = l >> 4;
        float so = 0.f, wo = 0.f, sa = 0.f, wa = 0.f;
#pragma unroll
        for (int i = 0; i < 16; ++i) {
            int ff = j * 16 + i;
            float r1v = r1s[ff];
            float lg = __log2f(clip01(p1[c * NF + ff]) + EPSN);
            float z = KL * r1v;
            float eo = fexp2(z + lg);
            float ea = fexp2(lg - z);
            so += eo; wo = fmaf(eo, r1v, wo);
            sa += ea; wa = fmaf(ea, r1v, wa);
        }
#pragma unroll
        for (int d = 16; d < 64; d <<= 1) {
            so += __shfl_xor(so, d);
            wo += __shfl_xor(wo, d);
            sa += __shfl_xor(sa, d);
            wa += __shfl_xor(wa, d);
        }
        if (l < NC) {
            float tvl1 = clip01(tvl1_[l]);
            r2s[l] = tvl1 * (wo / so) + (1.0f - tvl1) * (wa / sa);
        }
    }

    // stage 3: lane 0
    if (l == 0) {
        float so = 0.f, wo = 0.f, sa = 0.f, wa = 0.f;
#pragma unroll
        for (int c = 0; c < NC; ++c) {
            float lg = __log2f(clip01(p2[c]) + EPSN);
            float r2v = r2s[c];
            float z = KL * r2v;
            float eo = fexp2(z + lg);
            float ea = fexp2(lg - z);
            so += eo; wo = fmaf(eo, r2v, wo);
            sa += ea; wa = fmaf(ea, r2v, wa);
        }
        float tvl2 = clip01(tvl2_[0]);
        out[b] = tvl2 * (wo / so) + (1.0f - tvl2) * (wa / sa);
    }
}

// ---------------------------------------------------------------------------
// Fallback: R6's validated single kernel (inline w), used when ws too small.
// ---------------------------------------------------------------------------
__global__ __launch_bounds__(TPB) void fused_inline(
    const float* __restrict__ x, const float* __restrict__ t1g,
    const float* __restrict__ t2g, const float* __restrict__ av,
    const float* __restrict__ bv, const float* __restrict__ p1,
    const float* __restrict__ p2, const float* __restrict__ tvt_,
    const float* __restrict__ tvl1_, const float* __restrict__ tvl2_,
    float* __restrict__ out) {
    __shared__ float4 redQ[NQ][NF];
    __shared__ float r1s[NF];
    __shared__ float r2s[NC];

    const int b = blockIdx.x;
    const int tid = threadIdx.x;
    const int f = tid & (NF - 1);
    const int q = tid >> 6;
    const int ch = f & 1;

    const float B2 = BETA * LOG2E;
    const float KL = KAPPA * LOG2E;
    const float A2 = B2 * av[f];

    float t1c = fminf(fmaxf(t1g[f], 0.0f), (float)(LEN - 1));
    float t2c = fminf(fmaxf(t2g[f], 0.0f), (float)(LEN - 1));
    t1c = fminf(t1c, t2c - 1.0f);
    const float c1 = B2 * t1c;
    const float c2 = -B2 * t2c;

    const int t0 = q * CHUNK;
    const float4* xp4 = (const float4*)(x + (size_t)b * (LEN * 2) + 2 * t0);

    float Sp0 = 0.f, Xp0 = 0.f, Sm0 = 0.f, Xm0 = 0.f;
    float Sp1 = 0.f, Xp1 = 0.f, Sm1 = 0.f, Xm1 = 0.f;
#pragma unroll 4
    for (int k2 = 0; k2 < CHUNK / 2; ++k2) {
        float4 v = xp4[k2];
        float xa = ch ? v.y : v.x;
        float xb = ch ? v.w : v.z;
        float tfa = (float)(t0 + 2 * k2);
        float tfb = tfa + 1.0f;
        {
            float g1 = fmaf(-B2, tfa, c1);
            float g2 = fmaf(B2, tfa, c2);
            float den = (1.0f + fexp2(g1)) * (1.0f + fexp2(g2));
            float w = frcp(den);
            float P = fexp2(A2 * xa);
            float Pm = frcp(P);
            float tp = P * w, tm = Pm * w;
            Sp0 += tp; Xp0 = fmaf(tp, xa, Xp0);
            Sm0 += tm; Xm0 = fmaf(tm, xa, Xm0);
        }
        {
            float g1 = fmaf(-B2, tfb, c1);
            float g2 = fmaf(B2, tfb, c2);
            float den = (1.0f + fexp2(g1)) * (1.0f + fexp2(g2));
            float w = frcp(den);
            float P = fexp2(A2 * xb);
            float Pm = frcp(P);
            float tp = P * w, tm = Pm * w;
            Sp1 += tp; Xp1 = fmaf(tp, xb, Xp1);
            Sm1 += tm; Xm1 = fmaf(tm, xb, Xm1);
        }
    }

    redQ[q][f] = make_float4(Sp0 + Sp1, Xp0 + Xp1, Sm0 + Sm1, Xm0 + Xm1);

    if (b == 0 && q == NQ - 1) {
        const int l = f;
        float acc = 0.0f;
#pragma unroll
        for (int i = 0; i < 16; ++i) {
            float p = clip01(p1[i * NF + l]);
            acc += 0.01f * (p * (1.0f - p)) + 0.01f * (p * p);
        }
        {
            float c = clip01(tvt_[l]);
            acc += 0.01f * (c * (1.0f - c));
        }
        if (l < NC) {
            float p = clip01(p2[l]);
            acc += 0.01f * (p * (1.0f - p)) + 0.01f * (p * p);
            float c = clip01(tvl1_[l]);
            acc += 0.01f * (c * (1.0f - c));
        }
        if (l == 0) {
            float c = clip01(tvl2_[0]);
            acc += 0.01f * (c * (1.0f - c));
        }
#pragma unroll
        for (int d = 1; d < 64; d <<= 1) acc += __shfl_xor(acc, d);
        if (l == 0) out[BATCH] = acc;
    }

    __syncthreads();
    if (tid >= 64) return;

    const int l = tid;
    float ax = 0.f, ay = 0.f, az = 0.f, aw = 0.f;
#pragma unroll
    for (int s = 0; s < NQ; ++s) {
        float4 v = redQ[s][l];
        ax += v.x; ay += v.y; az += v.z; aw += v.w;
    }
    {
        float af = av[l], bf = bv[l];
        float tvt = clip01(tvt_[l]);
        float rmax = af * (ay / ax);
        float rmin = af * (aw / az);
        r1s[l] = tvt * rmax + (1.0f - tvt) * rmin - bf;
    }
    {
        const int c = l & 15;
        const int j = l >> 4;
        float so = 0.f, wo = 0.f, sa = 0.f, wa = 0.f;
#pragma unroll
        for (int i = 0; i < 16; ++i) {
            int ff = j * 16 + i;
            float r1v = r1s[ff];
            float lg = __log2f(clip01(p1[c * NF + ff]) + EPSN);
            float z = KL * r1v;
            float eo = fexp2(z + lg);
            float ea = fexp2(lg - z);
            so += eo; wo = fmaf(eo, r1v, wo);
            sa += ea; wa = fmaf(ea, r1v, wa);
        }
#pragma unroll
        for (int d = 16; d < 64; d <<= 1) {
            so += __shfl_xor(so, d);
            wo += __shfl_xor(wo, d);
            sa += __shfl_xor(sa, d);
            wa += __shfl_xor(wa, d);
        }
        if (l < NC) {
            float tvl1 = clip01(tvl1_[l]);
            r2s[l] = tvl1 * (wo / so) + (1.0f - tvl1) * (wa / sa);
        }
    }
    if (l == 0) {
        float so = 0.f, wo = 0.f, sa = 0.f, wa = 0.f;
#pragma unroll
        for (int c = 0; c < NC; ++c) {
            float lg = __log2f(clip01(p2[c]) + EPSN);
            float r2v = r2s[c];
            float z = KL * r2v;
            float eo = fexp2(z + lg);
            float ea = fexp2(lg - z);
            so += eo; wo = fmaf(eo, r2v, wo);
            sa += ea; wa = fmaf(ea, r2v, wa);
        }
        float tvl2 = clip01(tvl2_[0]);
        out[b] = tvl2 * (wo / so) + (1.0f - tvl2) * (wa / sa);
    }
}

// ---------------------------------------------------------------------------
extern "C" void kernel_launch(void* const* d_in, const int* in_sizes, int n_in,
                              void* d_out, int out_size, void* d_ws, size_t ws_size,
                              hipStream_t stream) {
    const float* x    = (const float*)d_in[0];
    const float* t1   = (const float*)d_in[1];
    const float* t2   = (const float*)d_in[2];
    const float* a    = (const float*)d_in[3];
    const float* bv   = (const float*)d_in[4];
    const float* p1   = (const float*)d_in[5];
    const float* p2   = (const float*)d_in[6];
    const float* tvt  = (const float*)d_in[7];
    const float* tvl1 = (const float*)d_in[8];
    const float* tvl2 = (const float*)d_in[9];
    float* out = (float*)d_out;

    const size_t lw_bytes = (size_t)(NF * LEN) * sizeof(float);   // 512 KB

    if (d_ws && ws_size >= lw_bytes) {
        float4* lwT4 = (float4*)d_ws;
        lw_reg_kernel<<<LW_BLOCKS + 1, 256, 0, stream>>>(t1, t2, p1, p2, tvt, tvl1,
                                                         tvl2, lwT4, out);
        fused_main<<<BATCH, TPB, 0, stream>>>(x, lwT4, a, bv, p1, p2,
                                              tvt, tvl1, tvl2, out);
    } else {
        fused_inline<<<BATCH, TPB, 0, stream>>>(x, t1, t2, a, bv, p1, p2,
                                                tvt, tvl1, tvl2, out);
    }
}